// Round 5
// baseline (86.306 us; speedup 1.0000x reference)
//
#include <hip/hip_runtime.h>
#include <math.h>

#define B_   2
#define C_   3
#define HW_  1024
#define N_   4096
#define AC_  12

#define PI_F    3.14159265358979323846f
#define L2E     1.4426950408889634f   // log2(e)
#define INV_L2E 0.6931471805599453f   // ln(2)

#define OUT0_ELEMS 24576   // B*A*C*H*W
#define OUT1_ELEMS 57344   // B*A*7*H*W
#define OUT2_ELEMS 18432   // B*C*3*H*W

// Fused single-kernel, workspace-free, exp-factored (r4 math kept verbatim).
// KEY CHANGE vs r4: pure occupancy. r4 ran 256 blocks = 1 block/CU =
// 2 waves/SIMD; VALUBusy 65% = dep-chain stalls with too few waves to
// interleave. Now ROWBLK=16 -> 512 main blocks = 2 blocks/CU = 4 waves/SIMD,
// with the SAME 2-rows/thread quad-folded inner body (r2's occupancy test
// was confounded by also switching to 1 row/thread).
// Anchor-slot rotation ((u+js)&3) keeps the 8-distinct-quad reads at <=2-way
// bank aliasing (free); without it they'd be 4-way (1.58x).
#define ROWBLK   16
#define JTILE    512
#define QTILE    128                  // quads per tile
#define NTILE    8                    // N_ / JTILE
#define MAINBLKS 512                  // B_ * (N_ / ROWBLK)
#define CPBLKS   32
#define CP_F4_BBOX 14336              // OUT1_ELEMS/4
#define CP_F4_TOT  18944              // (OUT1+OUT2)/4

#if __has_builtin(__builtin_amdgcn_exp2f)
#define EXP2F(x) __builtin_amdgcn_exp2f(x)
#else
#define EXP2F(x) __expf((x) * INV_L2E)
#endif

// Decode one row of `decoded` into a BEV corner box (x1,y1,x2,y2).
__device__ __forceinline__ float4 make_box(const float* __restrict__ d) {
    float x = d[0], y = d[1], d3 = d[3], d4 = d[4], rot = d[6];
    float kq = floorf(rot / PI_F + 0.5f);
    float normed = fabsf(rot - kq * PI_F);
    bool swap_wh = normed > (0.25f * PI_F);
    float w = swap_wh ? d4 : d3;
    float h = swap_wh ? d3 : d4;
    return make_float4(x - 0.5f * w, y - 0.5f * h, x + 0.5f * w, y + 0.5f * h);
}

// grid 544 x 512:
//   blocks [0,512): 16 rows (2/thread, sharing hw_i) x all-j aggregation.
//     r = t&7 (row slot -> rows 2r,2r+1), q = t>>3 (64 quad-subgroups).
//     Quads u = q + 64*mm. A wave covers 8 consecutive quads; the per-quad
//     slot rotation keeps its 8 distinct 16B reads at 2-way bank aliasing.
//   blocks [512,544): float4 passthrough copies of outputs 1 and 2.
// Softmax max-shifts dropped (cancel in num/(den*S)); values safe in f32.
__global__ __launch_bounds__(512) void k_fused(
    const float* __restrict__ scores, const float* __restrict__ pp,
    const float* __restrict__ dec, const float* __restrict__ bbox,
    float* __restrict__ out)
{
    const int blk = blockIdx.x;
    const int t = threadIdx.x;

    if (blk >= MAINBLKS) {
        const float4* src1 = (const float4*)bbox;
        const float4* src2 = (const float4*)pp;
        float4* dst1 = (float4*)(out + OUT0_ELEMS);
        float4* dst2 = (float4*)(out + OUT0_ELEMS + OUT1_ELEMS);
        for (int u = (blk - MAINBLKS) * 512 + t; u < CP_F4_TOT;
             u += CPBLKS * 512) {
            if (u < CP_F4_BBOX) dst1[u] = src1[u];
            else                dst2[u - CP_F4_BBOX] = src2[u - CP_F4_BBOX];
        }
        return;
    }

    const int b = blk >> 8;          // 256 row-blocks per batch
    const int rowblk = blk & 255;
    const int r = t & 7;
    const int q = t >> 3;            // [0,64)

    const float* __restrict__ decb = dec + b * (N_ * 7);
    const float* __restrict__ scb  = scores + b * (AC_ * HW_);
    const float* __restrict__ ppb  = pp + b * (9 * HW_);

    __shared__ float4 s_box[JTILE];                 // rotated-slot {x1,y1,x2,y2}
    __shared__ float4 s_aux[JTILE];                 // rotated-slot {area*ln2,e0,e1,e2}
    __shared__ float4 s_p1q[QTILE];                 // per-QUAD {p1_c0,c1,c2,-}
    __shared__ float2 s_red[8][ROWBLK][C_];         // wave, row, class
    __shared__ float  s_Sp[8][C_];                  // per-wave S partials

    // ---- row setup: rows 2r, 2r+1 share hw -> one p0 triple ----
    const int i0 = rowblk * ROWBLK + (r << 1);
    const float4 bx0 = make_box(decb + i0 * 7);
    const float4 bx1 = make_box(decb + (i0 + 1) * 7);
    const float ar0 = (bx0.z - bx0.x) * (bx0.w - bx0.y) * INV_L2E;
    const float ar1 = (bx1.z - bx1.x) * (bx1.w - bx1.y) * INV_L2E;
    const int hw0 = i0 >> 2;
    const float p0x = ppb[0 * HW_ + hw0] * L2E;
    const float p0y = ppb[3 * HW_ + hw0] * L2E;
    const float p0z = ppb[6 * HW_ + hw0] * L2E;

    float accn[2][C_] = {}, accd[2][C_] = {};
    float sS0 = 0.f, sS1 = 0.f, sS2 = 0.f;

    // rotated staging slot for this thread's j (j = tile*512 + t)
    const int su = t >> 2, sj = t & 3;
    const int sslot = (su << 2) | ((su + sj) & 3);

    // staging registers (1 j per thread; threads <128 also stage a p1-quad)
    float ld0, ld1, ld3, ld4, ld6, ls0, ls1, ls2, lq1a = 0.f, lq1b = 0.f, lq1c = 0.f;
    {   // preload tile 0
        const float* dj = decb + t * 7;
        ld0 = dj[0]; ld1 = dj[1]; ld3 = dj[3]; ld4 = dj[4]; ld6 = dj[6];
        const int hw = t >> 2, a = t & 3;
        ls0 = scb[(a * C_ + 0) * HW_ + hw];
        ls1 = scb[(a * C_ + 1) * HW_ + hw];
        ls2 = scb[(a * C_ + 2) * HW_ + hw];
        if (t < QTILE) {
            lq1a = ppb[1 * HW_ + t]; lq1b = ppb[4 * HW_ + t]; lq1c = ppb[7 * HW_ + t];
        }
    }

    for (int tile = 0; tile < NTILE; ++tile) {
        if (tile) __syncthreads();       // prior tile's readers done
        {   // decode + publish staged tile; accumulate S (each j once/block)
            float kq = floorf(ld6 / PI_F + 0.5f);
            float nr = fabsf(ld6 - kq * PI_F);
            bool sw = nr > (0.25f * PI_F);
            float w = sw ? ld4 : ld3, h = sw ? ld3 : ld4;
            float4 box = make_float4(ld0 - 0.5f * w, ld1 - 0.5f * h,
                                     ld0 + 0.5f * w, ld1 + 0.5f * h);
            float area = (box.z - box.x) * (box.w - box.y);
            float e0 = __expf(ls0), e1 = __expf(ls1), e2 = __expf(ls2);
            sS0 += e0; sS1 += e1; sS2 += e2;
            s_box[sslot] = box;
            s_aux[sslot] = make_float4(area * INV_L2E, e0, e1, e2);
            if (t < QTILE) s_p1q[t] = make_float4(lq1a, lq1b, lq1c, 0.f);
        }
        __syncthreads();
        if (tile + 1 < NTILE) {          // prefetch next tile under compute
            const int j = (tile + 1) * JTILE + t;
            const float* dj = decb + j * 7;
            ld0 = dj[0]; ld1 = dj[1]; ld3 = dj[3]; ld4 = dj[4]; ld6 = dj[6];
            const int hw = j >> 2, a = j & 3;
            ls0 = scb[(a * C_ + 0) * HW_ + hw];
            ls1 = scb[(a * C_ + 1) * HW_ + hw];
            ls2 = scb[(a * C_ + 2) * HW_ + hw];
            if (t < QTILE) {
                const int uq = (tile + 1) * QTILE + t;
                lq1a = ppb[1 * HW_ + uq]; lq1b = ppb[4 * HW_ + uq]; lq1c = ppb[7 * HW_ + uq];
            }
        }
#pragma unroll
        for (int mm = 0; mm < QTILE / 64; ++mm) {
            const int u = q + (mm << 6);
            const float4 pq = s_p1q[u];
            const float g0 = EXP2F(p0x * pq.x);
            const float g1 = EXP2F(p0y * pq.y);
            const float g2 = EXP2F(p0z * pq.z);
            const int ub = u << 2, ur = u & 3;
            float Eq0 = 0.f, Eq1 = 0.f;
            float t00 = 0.f, t01 = 0.f, t02 = 0.f;
            float t10 = 0.f, t11 = 0.f, t12 = 0.f;
#pragma unroll
            for (int js = 0; js < 4; ++js) {
                const int jj = ub | ((ur + js) & 3);
                const float4 bj = s_box[jj];
                const float4 ax = s_aux[jj];   // {area_j*ln2, e0, e1, e2}
                {   // row 0
                    float x1 = fmaxf(bx0.x, bj.x), y1 = fmaxf(bx0.y, bj.y);
                    float x2 = fminf(bx0.z, bj.z), y2 = fminf(bx0.w, bj.w);
                    float w = fmaxf(x2 - x1, 0.f), h = fmaxf(y2 - y1, 0.f);
                    float inter = w * h;
                    float uni = fmaf(inter, -INV_L2E, ar0 + ax.x); // ln2*union
                    float E = EXP2F(inter * __builtin_amdgcn_rcpf(uni));
                    Eq0 += E;
                    t00 = fmaf(E, ax.y, t00);
                    t01 = fmaf(E, ax.z, t01);
                    t02 = fmaf(E, ax.w, t02);
                }
                {   // row 1
                    float x1 = fmaxf(bx1.x, bj.x), y1 = fmaxf(bx1.y, bj.y);
                    float x2 = fminf(bx1.z, bj.z), y2 = fminf(bx1.w, bj.w);
                    float w = fmaxf(x2 - x1, 0.f), h = fmaxf(y2 - y1, 0.f);
                    float inter = w * h;
                    float uni = fmaf(inter, -INV_L2E, ar1 + ax.x);
                    float E = EXP2F(inter * __builtin_amdgcn_rcpf(uni));
                    Eq1 += E;
                    t10 = fmaf(E, ax.y, t10);
                    t11 = fmaf(E, ax.z, t11);
                    t12 = fmaf(E, ax.w, t12);
                }
            }
            // fold quad into running totals (per row, per class)
            accd[0][0] = fmaf(g0, Eq0, accd[0][0]);
            accd[0][1] = fmaf(g1, Eq0, accd[0][1]);
            accd[0][2] = fmaf(g2, Eq0, accd[0][2]);
            accn[0][0] = fmaf(g0, t00, accn[0][0]);
            accn[0][1] = fmaf(g1, t01, accn[0][1]);
            accn[0][2] = fmaf(g2, t02, accn[0][2]);
            accd[1][0] = fmaf(g0, Eq1, accd[1][0]);
            accd[1][1] = fmaf(g1, Eq1, accd[1][1]);
            accd[1][2] = fmaf(g2, Eq1, accd[1][2]);
            accn[1][0] = fmaf(g0, t10, accn[1][0]);
            accn[1][1] = fmaf(g1, t11, accn[1][1]);
            accn[1][2] = fmaf(g2, t12, accn[1][2]);
        }
    }

    // ---- reduce the 8 q-values (lane bits 3..5) inside each wave ----
    const int wv = t >> 6, lane = t & 63;
#pragma unroll
    for (int k = 0; k < 2; ++k)
#pragma unroll
        for (int c = 0; c < C_; ++c) {
            float nv = accn[k][c], dv = accd[k][c];
            nv += __shfl_xor(nv, 8);  dv += __shfl_xor(dv, 8);
            nv += __shfl_xor(nv, 16); dv += __shfl_xor(dv, 16);
            nv += __shfl_xor(nv, 32); dv += __shfl_xor(dv, 32);
            if (lane < 8) s_red[wv][(lane << 1) + k][c] = make_float2(nv, dv);
        }
#pragma unroll
    for (int off = 1; off < 64; off <<= 1) {
        sS0 += __shfl_xor(sS0, off);
        sS1 += __shfl_xor(sS1, off);
        sS2 += __shfl_xor(sS2, off);
    }
    if (lane == 0) { s_Sp[wv][0] = sS0; s_Sp[wv][1] = sS1; s_Sp[wv][2] = sS2; }
    __syncthreads();

    // ---- final: 48 (row,c) outputs per block ----
    if (t < C_ * ROWBLK) {
        const int c = t >> 4, row = t & 15;
        float num = 0.f, den = 0.f, S = 0.f;
#pragma unroll
        for (int w = 0; w < 8; ++w) {
            float2 v = s_red[w][row][c];
            num += v.x; den += v.y;
            S += s_Sp[w][c];
        }
        const int n = rowblk * ROWBLK + row;
        out[(b * AC_ + (n & 3) * C_ + c) * HW_ + (n >> 2)] = num / (den * S);
    }
}

extern "C" void kernel_launch(void* const* d_in, const int* in_sizes, int n_in,
                              void* d_out, int out_size, void* d_ws, size_t ws_size,
                              hipStream_t stream) {
    (void)d_ws; (void)ws_size;
    const float* scores = (const float*)d_in[0];
    const float* bbox   = (const float*)d_in[1];
    const float* pp     = (const float*)d_in[2];
    const float* dec    = (const float*)d_in[3];
    k_fused<<<MAINBLKS + CPBLKS, 512, 0, stream>>>(
        scores, pp, dec, bbox, (float*)d_out);
}

// Round 6
// 86.189 us; speedup vs baseline: 1.0014x; 1.0014x over previous
//
#include <hip/hip_runtime.h>
#include <math.h>

#define B_   2
#define C_   3
#define HW_  1024
#define N_   4096
#define AC_  12

#define PI_F    3.14159265358979323846f
#define L2E     1.4426950408889634f   // log2(e)
#define INV_L2E 0.6931471805599453f   // ln(2)

#define OUT0_ELEMS 24576   // B*A*C*H*W
#define OUT1_ELEMS 57344   // B*A*7*H*W
#define OUT2_ELEMS 18432   // B*C*3*H*W

// Fused single-kernel, workspace-free, exp-factored. KEY CHANGE vs r5
// (occupancy exonerated 2x: 2 vs 4 waves/SIMD identical): instruction diet.
// Each thread owns a FULL i-quad (4 rows sharing hw_i): the g-triple is
// shared over 16 pairs (was 8), the 2 ds_read_b128 + jj rotation amortize
// over 4 rows (was 2), and 256 blocks (not 512) halve redundant j-staging.
// Skeleton/barriers/rotation-layout identical to the verified r4/r5 kernel.
#define ROWBLK   32
#define RPT      4
#define JTILE    512
#define QTILE    128                  // quads per tile
#define NTILE    8                    // N_ / JTILE
#define MAINBLKS 256                  // B_ * (N_ / ROWBLK)
#define CPBLKS   32
#define CP_F4_BBOX 14336              // OUT1_ELEMS/4
#define CP_F4_TOT  18944              // (OUT1+OUT2)/4

#if __has_builtin(__builtin_amdgcn_exp2f)
#define EXP2F(x) __builtin_amdgcn_exp2f(x)
#else
#define EXP2F(x) __expf((x) * INV_L2E)
#endif

// Decode one row of `decoded` into a BEV corner box (x1,y1,x2,y2).
__device__ __forceinline__ float4 make_box(const float* __restrict__ d) {
    float x = d[0], y = d[1], d3 = d[3], d4 = d[4], rot = d[6];
    float kq = floorf(rot / PI_F + 0.5f);
    float normed = fabsf(rot - kq * PI_F);
    bool swap_wh = normed > (0.25f * PI_F);
    float w = swap_wh ? d4 : d3;
    float h = swap_wh ? d3 : d4;
    return make_float4(x - 0.5f * w, y - 0.5f * h, x + 0.5f * w, y + 0.5f * h);
}

// grid 288 x 512:
//   blocks [0,256): 32 rows (4/thread = one i-quad) x all-j aggregation.
//     r = t&7 (i-quad slot -> rows 4r..4r+3), q = t>>3 (64 quad-subgroups).
//     A wave spans 8 consecutive quads; the per-quad slot rotation spreads
//     its 8 distinct 16B reads across 8 bank-groups (conflict-free).
//   blocks [256,288): float4 passthrough copies of outputs 1 and 2.
// Softmax max-shifts dropped (cancel in num/(den*S)); values safe in f32.
__global__ __launch_bounds__(512) void k_fused(
    const float* __restrict__ scores, const float* __restrict__ pp,
    const float* __restrict__ dec, const float* __restrict__ bbox,
    float* __restrict__ out)
{
    const int blk = blockIdx.x;
    const int t = threadIdx.x;

    if (blk >= MAINBLKS) {
        const float4* src1 = (const float4*)bbox;
        const float4* src2 = (const float4*)pp;
        float4* dst1 = (float4*)(out + OUT0_ELEMS);
        float4* dst2 = (float4*)(out + OUT0_ELEMS + OUT1_ELEMS);
        for (int u = (blk - MAINBLKS) * 512 + t; u < CP_F4_TOT;
             u += CPBLKS * 512) {
            if (u < CP_F4_BBOX) dst1[u] = src1[u];
            else                dst2[u - CP_F4_BBOX] = src2[u - CP_F4_BBOX];
        }
        return;
    }

    const int b = blk >> 7;          // 128 row-blocks per batch
    const int rowblk = blk & 127;
    const int r = t & 7;
    const int q = t >> 3;            // [0,64)

    const float* __restrict__ decb = dec + b * (N_ * 7);
    const float* __restrict__ scb  = scores + b * (AC_ * HW_);
    const float* __restrict__ ppb  = pp + b * (9 * HW_);

    __shared__ float4 s_box[JTILE];                 // rotated-slot {x1,y1,x2,y2}
    __shared__ float4 s_aux[JTILE];                 // rotated-slot {area*ln2,e0,e1,e2}
    __shared__ float4 s_p1q[QTILE];                 // per-QUAD {p1_c0,c1,c2,-}
    __shared__ float2 s_red[8][ROWBLK][C_];         // wave, row, class
    __shared__ float  s_Sp[8][C_];                  // per-wave S partials

    // ---- row setup: one full i-quad (rows 4r..4r+3), one shared hw ----
    const int i0 = rowblk * ROWBLK + (r << 2);
    const int hw0 = i0 >> 2;                        // = rowblk*8 + r
    float4 bx[RPT]; float ar[RPT];
#pragma unroll
    for (int k = 0; k < RPT; ++k) {
        bx[k] = make_box(decb + (i0 + k) * 7);
        ar[k] = (bx[k].z - bx[k].x) * (bx[k].w - bx[k].y) * INV_L2E;
    }
    const float p0x = ppb[0 * HW_ + hw0] * L2E;
    const float p0y = ppb[3 * HW_ + hw0] * L2E;
    const float p0z = ppb[6 * HW_ + hw0] * L2E;

    float accn[RPT][C_] = {}, accd[RPT][C_] = {};
    float sS0 = 0.f, sS1 = 0.f, sS2 = 0.f;

    // rotated staging slot for this thread's j (j = tile*512 + t)
    const int su = t >> 2, sj = t & 3;
    const int sslot = (su << 2) | ((su + sj) & 3);

    // staging registers (1 j per thread; threads <128 also stage a p1-quad)
    float ld0, ld1, ld3, ld4, ld6, ls0, ls1, ls2, lq1a = 0.f, lq1b = 0.f, lq1c = 0.f;
    {   // preload tile 0
        const float* dj = decb + t * 7;
        ld0 = dj[0]; ld1 = dj[1]; ld3 = dj[3]; ld4 = dj[4]; ld6 = dj[6];
        const int hw = t >> 2, a = t & 3;
        ls0 = scb[(a * C_ + 0) * HW_ + hw];
        ls1 = scb[(a * C_ + 1) * HW_ + hw];
        ls2 = scb[(a * C_ + 2) * HW_ + hw];
        if (t < QTILE) {
            lq1a = ppb[1 * HW_ + t]; lq1b = ppb[4 * HW_ + t]; lq1c = ppb[7 * HW_ + t];
        }
    }

    for (int tile = 0; tile < NTILE; ++tile) {
        if (tile) __syncthreads();       // prior tile's readers done
        {   // decode + publish staged tile; accumulate S (each j once/block)
            float kq = floorf(ld6 / PI_F + 0.5f);
            float nr = fabsf(ld6 - kq * PI_F);
            bool sw = nr > (0.25f * PI_F);
            float w = sw ? ld4 : ld3, h = sw ? ld3 : ld4;
            float4 box = make_float4(ld0 - 0.5f * w, ld1 - 0.5f * h,
                                     ld0 + 0.5f * w, ld1 + 0.5f * h);
            float area = (box.z - box.x) * (box.w - box.y);
            float e0 = __expf(ls0), e1 = __expf(ls1), e2 = __expf(ls2);
            sS0 += e0; sS1 += e1; sS2 += e2;
            s_box[sslot] = box;
            s_aux[sslot] = make_float4(area * INV_L2E, e0, e1, e2);
            if (t < QTILE) s_p1q[t] = make_float4(lq1a, lq1b, lq1c, 0.f);
        }
        __syncthreads();
        if (tile + 1 < NTILE) {          // prefetch next tile under compute
            const int j = (tile + 1) * JTILE + t;
            const float* dj = decb + j * 7;
            ld0 = dj[0]; ld1 = dj[1]; ld3 = dj[3]; ld4 = dj[4]; ld6 = dj[6];
            const int hw = j >> 2, a = j & 3;
            ls0 = scb[(a * C_ + 0) * HW_ + hw];
            ls1 = scb[(a * C_ + 1) * HW_ + hw];
            ls2 = scb[(a * C_ + 2) * HW_ + hw];
            if (t < QTILE) {
                const int uq = (tile + 1) * QTILE + t;
                lq1a = ppb[1 * HW_ + uq]; lq1b = ppb[4 * HW_ + uq]; lq1c = ppb[7 * HW_ + uq];
            }
        }
#pragma unroll
        for (int mm = 0; mm < QTILE / 64; ++mm) {
            const int u = q + (mm << 6);
            const float4 pq = s_p1q[u];
            const float g0 = EXP2F(p0x * pq.x);
            const float g1 = EXP2F(p0y * pq.y);
            const float g2 = EXP2F(p0z * pq.z);
            const int ub = u << 2, ur = u & 3;
            float Eq[RPT] = {};
            float tt[RPT][C_] = {};
#pragma unroll
            for (int js = 0; js < 4; ++js) {
                const int jj = ub | ((ur + js) & 3);
                const float4 bj = s_box[jj];
                const float4 ax = s_aux[jj];   // {area_j*ln2, e0, e1, e2}
#pragma unroll
                for (int k = 0; k < RPT; ++k) {
                    float x1 = fmaxf(bx[k].x, bj.x), y1 = fmaxf(bx[k].y, bj.y);
                    float x2 = fminf(bx[k].z, bj.z), y2 = fminf(bx[k].w, bj.w);
                    float w = fmaxf(x2 - x1, 0.f), h = fmaxf(y2 - y1, 0.f);
                    float inter = w * h;
                    float uni = fmaf(inter, -INV_L2E, ar[k] + ax.x); // ln2*union
                    float E = EXP2F(inter * __builtin_amdgcn_rcpf(uni));
                    Eq[k] += E;
                    tt[k][0] = fmaf(E, ax.y, tt[k][0]);
                    tt[k][1] = fmaf(E, ax.z, tt[k][1]);
                    tt[k][2] = fmaf(E, ax.w, tt[k][2]);
                }
            }
            // fold quad into running totals (per row, per class)
#pragma unroll
            for (int k = 0; k < RPT; ++k) {
                accd[k][0] = fmaf(g0, Eq[k], accd[k][0]);
                accd[k][1] = fmaf(g1, Eq[k], accd[k][1]);
                accd[k][2] = fmaf(g2, Eq[k], accd[k][2]);
                accn[k][0] = fmaf(g0, tt[k][0], accn[k][0]);
                accn[k][1] = fmaf(g1, tt[k][1], accn[k][1]);
                accn[k][2] = fmaf(g2, tt[k][2], accn[k][2]);
            }
        }
    }

    // ---- reduce the 8 q-values (lane bits 3..5) inside each wave ----
    const int wv = t >> 6, lane = t & 63;
#pragma unroll
    for (int k = 0; k < RPT; ++k)
#pragma unroll
        for (int c = 0; c < C_; ++c) {
            float nv = accn[k][c], dv = accd[k][c];
            nv += __shfl_xor(nv, 8);  dv += __shfl_xor(dv, 8);
            nv += __shfl_xor(nv, 16); dv += __shfl_xor(dv, 16);
            nv += __shfl_xor(nv, 32); dv += __shfl_xor(dv, 32);
            if (lane < 8) s_red[wv][(lane << 2) + k][c] = make_float2(nv, dv);
        }
#pragma unroll
    for (int off = 1; off < 64; off <<= 1) {
        sS0 += __shfl_xor(sS0, off);
        sS1 += __shfl_xor(sS1, off);
        sS2 += __shfl_xor(sS2, off);
    }
    if (lane == 0) { s_Sp[wv][0] = sS0; s_Sp[wv][1] = sS1; s_Sp[wv][2] = sS2; }
    __syncthreads();

    // ---- final: 96 (row,c) outputs per block ----
    if (t < C_ * ROWBLK) {
        const int c = t >> 5, row = t & 31;
        float num = 0.f, den = 0.f, S = 0.f;
#pragma unroll
        for (int w = 0; w < 8; ++w) {
            float2 v = s_red[w][row][c];
            num += v.x; den += v.y;
            S += s_Sp[w][c];
        }
        const int n = rowblk * ROWBLK + row;
        out[(b * AC_ + (n & 3) * C_ + c) * HW_ + (n >> 2)] = num / (den * S);
    }
}

extern "C" void kernel_launch(void* const* d_in, const int* in_sizes, int n_in,
                              void* d_out, int out_size, void* d_ws, size_t ws_size,
                              hipStream_t stream) {
    (void)d_ws; (void)ws_size;
    const float* scores = (const float*)d_in[0];
    const float* bbox   = (const float*)d_in[1];
    const float* pp     = (const float*)d_in[2];
    const float* dec    = (const float*)d_in[3];
    k_fused<<<MAINBLKS + CPBLKS, 512, 0, stream>>>(
        scores, pp, dec, bbox, (float*)d_out);
}

// Round 7
// 83.443 us; speedup vs baseline: 1.0343x; 1.0329x over previous
//
#include <hip/hip_runtime.h>
#include <math.h>

#define B_   2
#define C_   3
#define HW_  1024
#define N_   4096
#define AC_  12

#define PI_F    3.14159265358979323846f
#define L2E     1.4426950408889634f   // log2(e)
#define INV_L2E 0.6931471805599453f   // ln(2)

#define OUT0_ELEMS 24576   // B*A*C*H*W
#define OUT1_ELEMS 57344   // B*A*7*H*W
#define OUT2_ELEMS 18432   // B*C*3*H*W

// Fused single-kernel, workspace-free, exp-factored. KEY CHANGE vs r6:
// packed FP32. gfx950's 157 TF fp32 = 2x scalar rate via v_pk_{fma,mul,add}
// _f32 (VOP3P). The thread's 4 rows are paired into 2x f32x2 vectors; the
// sub/mul/add/fma portion of the IoU core (10 of 16 VALU/pair) and the
// quad-fold fmas emit as pk ops (min/max stay scalar - no pk form). Same
// per-element arithmetic; structure/barriers/layout identical to r6.
#define ROWBLK   32
#define RPT      4
#define JTILE    512
#define QTILE    128                  // quads per tile
#define NTILE    8                    // N_ / JTILE
#define MAINBLKS 256                  // B_ * (N_ / ROWBLK)
#define CPBLKS   32
#define CP_F4_BBOX 14336              // OUT1_ELEMS/4
#define CP_F4_TOT  18944              // (OUT1+OUT2)/4

#if __has_builtin(__builtin_amdgcn_exp2f)
#define EXP2F(x) __builtin_amdgcn_exp2f(x)
#else
#define EXP2F(x) __expf((x) * INV_L2E)
#endif

typedef float f32x2 __attribute__((ext_vector_type(2)));

__device__ __forceinline__ f32x2 vmax2(f32x2 a, f32x2 b) {
    f32x2 r; r.x = fmaxf(a.x, b.x); r.y = fmaxf(a.y, b.y); return r;
}
__device__ __forceinline__ f32x2 vmin2(f32x2 a, f32x2 b) {
    f32x2 r; r.x = fminf(a.x, b.x); r.y = fminf(a.y, b.y); return r;
}

// Decode one row of `decoded` into a BEV corner box (x1,y1,x2,y2).
__device__ __forceinline__ float4 make_box(const float* __restrict__ d) {
    float x = d[0], y = d[1], d3 = d[3], d4 = d[4], rot = d[6];
    float kq = floorf(rot / PI_F + 0.5f);
    float normed = fabsf(rot - kq * PI_F);
    bool swap_wh = normed > (0.25f * PI_F);
    float w = swap_wh ? d4 : d3;
    float h = swap_wh ? d3 : d4;
    return make_float4(x - 0.5f * w, y - 0.5f * h, x + 0.5f * w, y + 0.5f * h);
}

// grid 288 x 512:
//   blocks [0,256): 32 rows (4/thread = one i-quad, held as 2x f32x2 row
//     pairs) x all-j aggregation. r = t&7 (i-quad slot -> rows 4r..4r+3),
//     q = t>>3 (64 quad-subgroups). A wave spans 8 consecutive quads; the
//     per-quad slot rotation spreads its 8 distinct 16B reads across 8
//     bank-groups (conflict-free).
//   blocks [256,288): float4 passthrough copies of outputs 1 and 2.
// Softmax max-shifts dropped (cancel in num/(den*S)); values safe in f32.
__global__ __launch_bounds__(512) void k_fused(
    const float* __restrict__ scores, const float* __restrict__ pp,
    const float* __restrict__ dec, const float* __restrict__ bbox,
    float* __restrict__ out)
{
    const int blk = blockIdx.x;
    const int t = threadIdx.x;

    if (blk >= MAINBLKS) {
        const float4* src1 = (const float4*)bbox;
        const float4* src2 = (const float4*)pp;
        float4* dst1 = (float4*)(out + OUT0_ELEMS);
        float4* dst2 = (float4*)(out + OUT0_ELEMS + OUT1_ELEMS);
        for (int u = (blk - MAINBLKS) * 512 + t; u < CP_F4_TOT;
             u += CPBLKS * 512) {
            if (u < CP_F4_BBOX) dst1[u] = src1[u];
            else                dst2[u - CP_F4_BBOX] = src2[u - CP_F4_BBOX];
        }
        return;
    }

    const int b = blk >> 7;          // 128 row-blocks per batch
    const int rowblk = blk & 127;
    const int r = t & 7;
    const int q = t >> 3;            // [0,64)

    const float* __restrict__ decb = dec + b * (N_ * 7);
    const float* __restrict__ scb  = scores + b * (AC_ * HW_);
    const float* __restrict__ ppb  = pp + b * (9 * HW_);

    __shared__ float4 s_box[JTILE];                 // rotated-slot {x1,y1,x2,y2}
    __shared__ float4 s_aux[JTILE];                 // rotated-slot {area*ln2,e0,e1,e2}
    __shared__ float4 s_p1q[QTILE];                 // per-QUAD {p1_c0,c1,c2,-}
    __shared__ float2 s_red[8][ROWBLK][C_];         // wave, row, class
    __shared__ float  s_Sp[8][C_];                  // per-wave S partials

    // ---- row setup: one full i-quad (rows 4r..4r+3), one shared hw ----
    const int i0 = rowblk * ROWBLK + (r << 2);
    const int hw0 = i0 >> 2;                        // = rowblk*8 + r
    // rows packed pairwise: pair p = rows (2p, 2p+1), components (.x, .y)
    f32x2 bxx[2], bxy[2], bxz[2], bxw[2], arv[2];
#pragma unroll
    for (int p = 0; p < 2; ++p) {
        float4 b0 = make_box(decb + (i0 + 2 * p) * 7);
        float4 b1 = make_box(decb + (i0 + 2 * p + 1) * 7);
        bxx[p] = f32x2{b0.x, b1.x};
        bxy[p] = f32x2{b0.y, b1.y};
        bxz[p] = f32x2{b0.z, b1.z};
        bxw[p] = f32x2{b0.w, b1.w};
        arv[p] = f32x2{(b0.z - b0.x) * (b0.w - b0.y) * INV_L2E,
                       (b1.z - b1.x) * (b1.w - b1.y) * INV_L2E};
    }
    const float p0x = ppb[0 * HW_ + hw0] * L2E;
    const float p0y = ppb[3 * HW_ + hw0] * L2E;
    const float p0z = ppb[6 * HW_ + hw0] * L2E;

    f32x2 accn[2][C_] = {}, accd[2][C_] = {};
    float sS0 = 0.f, sS1 = 0.f, sS2 = 0.f;

    // rotated staging slot for this thread's j (j = tile*512 + t)
    const int su = t >> 2, sj = t & 3;
    const int sslot = (su << 2) | ((su + sj) & 3);

    // staging registers (1 j per thread; threads <128 also stage a p1-quad)
    float ld0, ld1, ld3, ld4, ld6, ls0, ls1, ls2, lq1a = 0.f, lq1b = 0.f, lq1c = 0.f;
    {   // preload tile 0
        const float* dj = decb + t * 7;
        ld0 = dj[0]; ld1 = dj[1]; ld3 = dj[3]; ld4 = dj[4]; ld6 = dj[6];
        const int hw = t >> 2, a = t & 3;
        ls0 = scb[(a * C_ + 0) * HW_ + hw];
        ls1 = scb[(a * C_ + 1) * HW_ + hw];
        ls2 = scb[(a * C_ + 2) * HW_ + hw];
        if (t < QTILE) {
            lq1a = ppb[1 * HW_ + t]; lq1b = ppb[4 * HW_ + t]; lq1c = ppb[7 * HW_ + t];
        }
    }

    for (int tile = 0; tile < NTILE; ++tile) {
        if (tile) __syncthreads();       // prior tile's readers done
        {   // decode + publish staged tile; accumulate S (each j once/block)
            float kq = floorf(ld6 / PI_F + 0.5f);
            float nr = fabsf(ld6 - kq * PI_F);
            bool sw = nr > (0.25f * PI_F);
            float w = sw ? ld4 : ld3, h = sw ? ld3 : ld4;
            float4 box = make_float4(ld0 - 0.5f * w, ld1 - 0.5f * h,
                                     ld0 + 0.5f * w, ld1 + 0.5f * h);
            float area = (box.z - box.x) * (box.w - box.y);
            float e0 = __expf(ls0), e1 = __expf(ls1), e2 = __expf(ls2);
            sS0 += e0; sS1 += e1; sS2 += e2;
            s_box[sslot] = box;
            s_aux[sslot] = make_float4(area * INV_L2E, e0, e1, e2);
            if (t < QTILE) s_p1q[t] = make_float4(lq1a, lq1b, lq1c, 0.f);
        }
        __syncthreads();
        if (tile + 1 < NTILE) {          // prefetch next tile under compute
            const int j = (tile + 1) * JTILE + t;
            const float* dj = decb + j * 7;
            ld0 = dj[0]; ld1 = dj[1]; ld3 = dj[3]; ld4 = dj[4]; ld6 = dj[6];
            const int hw = j >> 2, a = j & 3;
            ls0 = scb[(a * C_ + 0) * HW_ + hw];
            ls1 = scb[(a * C_ + 1) * HW_ + hw];
            ls2 = scb[(a * C_ + 2) * HW_ + hw];
            if (t < QTILE) {
                const int uq = (tile + 1) * QTILE + t;
                lq1a = ppb[1 * HW_ + uq]; lq1b = ppb[4 * HW_ + uq]; lq1c = ppb[7 * HW_ + uq];
            }
        }
#pragma unroll
        for (int mm = 0; mm < QTILE / 64; ++mm) {
            const int u = q + (mm << 6);
            const float4 pq = s_p1q[u];
            const float g0 = EXP2F(p0x * pq.x);
            const float g1 = EXP2F(p0y * pq.y);
            const float g2 = EXP2F(p0z * pq.z);
            const int ub = u << 2, ur = u & 3;
            f32x2 Eq[2] = {};
            f32x2 tt[2][C_] = {};
#pragma unroll
            for (int js = 0; js < 4; ++js) {
                const int jj = ub | ((ur + js) & 3);
                const float4 bj = s_box[jj];
                const float4 ax = s_aux[jj];   // {area_j*ln2, e0, e1, e2}
                const f32x2 bjx = {bj.x, bj.x}, bjy = {bj.y, bj.y};
                const f32x2 bjz = {bj.z, bj.z}, bjw = {bj.w, bj.w};
                const f32x2 axx = {ax.x, ax.x};
                const f32x2 aey = {ax.y, ax.y}, aez = {ax.z, ax.z};
                const f32x2 aew = {ax.w, ax.w};
#pragma unroll
                for (int p = 0; p < 2; ++p) {
                    f32x2 x1 = vmax2(bxx[p], bjx), y1 = vmax2(bxy[p], bjy);
                    f32x2 x2 = vmin2(bxz[p], bjz), y2 = vmin2(bxw[p], bjw);
                    f32x2 w = vmax2(x2 - x1, f32x2{0.f, 0.f});
                    f32x2 h = vmax2(y2 - y1, f32x2{0.f, 0.f});
                    f32x2 inter = w * h;                        // pk_mul
                    f32x2 uni = inter * f32x2{-INV_L2E, -INV_L2E}
                                + (arv[p] + axx);               // pk_fma+pk_add
                    f32x2 rv;
                    rv.x = __builtin_amdgcn_rcpf(uni.x);
                    rv.y = __builtin_amdgcn_rcpf(uni.y);
                    f32x2 iou = inter * rv;                     // pk_mul
                    f32x2 E;
                    E.x = EXP2F(iou.x);
                    E.y = EXP2F(iou.y);
                    Eq[p] += E;                                 // pk_add
                    tt[p][0] += E * aey;                        // pk_fma x3
                    tt[p][1] += E * aez;
                    tt[p][2] += E * aew;
                }
            }
            // fold quad into running totals (per row-pair, per class)
            const f32x2 gs0 = {g0, g0}, gs1 = {g1, g1}, gs2 = {g2, g2};
#pragma unroll
            for (int p = 0; p < 2; ++p) {
                accd[p][0] += gs0 * Eq[p];
                accd[p][1] += gs1 * Eq[p];
                accd[p][2] += gs2 * Eq[p];
                accn[p][0] += gs0 * tt[p][0];
                accn[p][1] += gs1 * tt[p][1];
                accn[p][2] += gs2 * tt[p][2];
            }
        }
    }

    // ---- reduce the 8 q-values (lane bits 3..5) inside each wave ----
    const int wv = t >> 6, lane = t & 63;
#pragma unroll
    for (int k = 0; k < RPT; ++k)
#pragma unroll
        for (int c = 0; c < C_; ++c) {
            float nv = (k & 1) ? accn[k >> 1][c].y : accn[k >> 1][c].x;
            float dv = (k & 1) ? accd[k >> 1][c].y : accd[k >> 1][c].x;
            nv += __shfl_xor(nv, 8);  dv += __shfl_xor(dv, 8);
            nv += __shfl_xor(nv, 16); dv += __shfl_xor(dv, 16);
            nv += __shfl_xor(nv, 32); dv += __shfl_xor(dv, 32);
            if (lane < 8) s_red[wv][(lane << 2) + k][c] = make_float2(nv, dv);
        }
#pragma unroll
    for (int off = 1; off < 64; off <<= 1) {
        sS0 += __shfl_xor(sS0, off);
        sS1 += __shfl_xor(sS1, off);
        sS2 += __shfl_xor(sS2, off);
    }
    if (lane == 0) { s_Sp[wv][0] = sS0; s_Sp[wv][1] = sS1; s_Sp[wv][2] = sS2; }
    __syncthreads();

    // ---- final: 96 (row,c) outputs per block ----
    if (t < C_ * ROWBLK) {
        const int c = t >> 5, row = t & 31;
        float num = 0.f, den = 0.f, S = 0.f;
#pragma unroll
        for (int w = 0; w < 8; ++w) {
            float2 v = s_red[w][row][c];
            num += v.x; den += v.y;
            S += s_Sp[w][c];
        }
        const int n = rowblk * ROWBLK + row;
        out[(b * AC_ + (n & 3) * C_ + c) * HW_ + (n >> 2)] = num / (den * S);
    }
}

extern "C" void kernel_launch(void* const* d_in, const int* in_sizes, int n_in,
                              void* d_out, int out_size, void* d_ws, size_t ws_size,
                              hipStream_t stream) {
    (void)d_ws; (void)ws_size;
    const float* scores = (const float*)d_in[0];
    const float* bbox   = (const float*)d_in[1];
    const float* pp     = (const float*)d_in[2];
    const float* dec    = (const float*)d_in[3];
    k_fused<<<MAINBLKS + CPBLKS, 512, 0, stream>>>(
        scores, pp, dec, bbox, (float*)d_out);
}